// Round 7
// baseline (198.196 us; speedup 1.0000x reference)
//
#include <hip/hip_runtime.h>
#include <hip/hip_bf16.h>

#define SEQ_LEN 2048
#define NBATCH 2
#define DM 1024
#define NH 16
#define HD 64
#define NR (NBATCH * SEQ_LEN)  // 4096 rows
#define NQKV (3 * DM)          // 3072 fused QKV cols
#define LDQK 2048              // QK buffer leading dim (Q cols 0..1023, K 1024..2047)

typedef __attribute__((ext_vector_type(8))) short bf16x8;
typedef __attribute__((ext_vector_type(4))) float f32x4;
typedef __attribute__((ext_vector_type(16))) float f32x16;

__device__ __forceinline__ short f2b(float f) {
    __hip_bfloat16 h = __float2bfloat16(f);
    return *reinterpret_cast<short*>(&h);
}

// async global->LDS 16B copy
__device__ __forceinline__ void gload_lds16(const void* g, void* l) {
    __builtin_amdgcn_global_load_lds(
        (const __attribute__((address_space(1))) unsigned int*)g,
        (__attribute__((address_space(3))) unsigned int*)l, 16, 0, 0);
}

// ---------------------------------------------------------------------------
// Fused fp32->bf16 conversion for all 5 inputs in one launch.
// ---------------------------------------------------------------------------
__global__ __launch_bounds__(256) void cvt_all(
    const float* __restrict__ x,  const float* __restrict__ wq,
    const float* __restrict__ wk, const float* __restrict__ wv,
    const float* __restrict__ wo,
    __hip_bfloat16* __restrict__ xb, __hip_bfloat16* __restrict__ wqkvb,
    __hip_bfloat16* __restrict__ wob) {
    int id = blockIdx.x;
    const float* src; __hip_bfloat16* dst;
    if (id < 4096) { src = x + (size_t)id * 1024; dst = xb + (size_t)id * 1024; }
    else {
        int k = id - 4096, seg = k >> 10;
        size_t off = (size_t)(k & 1023) * 1024;
        if      (seg == 0) { src = wq + off; dst = wqkvb + off; }
        else if (seg == 1) { src = wk + off; dst = wqkvb + (1u << 20) + off; }
        else if (seg == 2) { src = wv + off; dst = wqkvb + (2u << 20) + off; }
        else               { src = wo + off; dst = wob + off; }
    }
    int i = threadIdx.x * 4;
    float4 v = *(const float4*)(src + i);
    dst[i + 0] = __float2bfloat16(v.x);
    dst[i + 1] = __float2bfloat16(v.y);
    dst[i + 2] = __float2bfloat16(v.z);
    dst[i + 3] = __float2bfloat16(v.w);
}

__device__ __forceinline__ void store_c(float* p, float v) { *p = v; }
__device__ __forceinline__ void store_c(__hip_bfloat16* p, float v) {
    *p = __float2bfloat16(v);
}

// ---------------------------------------------------------------------------
// gemm256_qkv: QKb/Vtg = xb @ Wqkvb^T with fused RoPE + V-transpose.
// 256x256 tile, BK=64, 8 waves (2M x 4N, each owns 128x64), LDS 128 KB.
// 8-PHASE COUNTED-VMCNT SCHEDULE (T3+T4, m201 template):
//   iteration i computes K-tiles T0=2i (buf0, phases 0-3) and TB=2i+1
//   (buf1, phases 4-7); each phase = one C-quadrant (hm,hn) over full K=64.
//   Per phase: ds-read the quadrant's fragments (A-frags register-reused
//   across the hn-pair), stage 0-2 half-tiles of tiles T2/T3 via
//   global_load_lds, 16 MFMA (setprio-wrapped, T5), s_barrier. Stages are
//   placed >=1 barrier AFTER the target region's last read (race-free by
//   construction); loads stay in flight ACROSS barriers — the only waits
//   are vmcnt(4) at phase-3 end (tile TB resident) and vmcnt(6) at phase-7
//   end (tile T2 resident). Never vmcnt(0) in steady state.
// LDS regions As[buf][hm] = A rows {L*128+hm*64+r}, Bs[buf][hn] = B rows
// {g*64+hn*32+r}; 16B-chunk XOR swizzle (chunk ^ (row&7)) applied on the
// pre-swizzled global source (linear LDS dest) and on ds_read -> 2-way
// bank aliasing (free). Grid 192 flat, XCD-chunked decode.
// Epilogues (from the verified gemm128): by<8 -> RoPE (+0.125 Q scale),
// by>=8 -> V transposed into Vtg[b][h][d][s'] with key bits 2<->3 swapped.
// ---------------------------------------------------------------------------
__global__ __launch_bounds__(512) void gemm256_qkv(
    const __hip_bfloat16* __restrict__ A,
    const __hip_bfloat16* __restrict__ B,
    __hip_bfloat16* __restrict__ C,
    __hip_bfloat16* __restrict__ Vtg,
    const int* __restrict__ pos) {
    __shared__ __hip_bfloat16 As[2][2][64 * 128];  // [buf][hm][128 rows x 64 cols]
    __shared__ __hip_bfloat16 Bs[2][2][64 * 128];  // [buf][hn][128 rows x 64 cols]

    const int t    = threadIdx.x;
    const int wave = t >> 6;        // 0..7
    const int wm   = wave >> 2;     // 0..1 (M half)
    const int wn   = wave & 3;      // 0..3 (N quarter)
    const int lane = t & 63;
    const int quad = lane >> 4;
    const int l16  = lane & 15;
    const int K    = DM;            // 1024
    const int NT   = K >> 6;        // 16 K-tiles
    const int NI   = K >> 7;        // 8 iterations

    // XCD-chunked bijective decode (192 blocks, 24/XCD)
    const int wg = (blockIdx.x & 7) * 24 + (blockIdx.x >> 3);
    const int bx = wg & 15;         // M/256 = 16
    const int by = wg >> 4;         // NQKV/256 = 12
    const int m0 = bx * 256, n0 = by * 256;

    // staging: thread t covers region rows (t>>3) and (t>>3)+64, chunk t&7;
    // global source chunk pre-XOR'd by (row&7) so linear LDS write lands the
    // swizzled layout ((row&7) == ((t>>3)&7) for both rows).
    const int  t16  = t * 16;
    const int  scx8 = ((t & 7) ^ ((t >> 3) & 7)) * 8;
    const int  srA  = t >> 3;             // A region row (L=0)
    const int  gB   = (t >> 8) & 1;       // B group for L=0 (L=1 adds 2)
    const int  rB   = (t >> 3) & 31;      // B row within group

#define STAGE_A(BUF, HM, TT)                                                    \
    {                                                                           \
        const __hip_bfloat16* _s =                                              \
            A + (size_t)(m0 + (HM) * 64 + srA) * K + (TT) * 64 + scx8;          \
        gload_lds16(_s,               (char*)As[BUF][HM] + t16);                \
        gload_lds16(_s + (size_t)128 * K, (char*)As[BUF][HM] + t16 + 8192);     \
    }
#define STAGE_B(BUF, HN, TT)                                                    \
    {                                                                           \
        const __hip_bfloat16* _s =                                              \
            B + (size_t)(n0 + gB * 64 + (HN) * 32 + rB) * K + (TT) * 64 + scx8; \
        gload_lds16(_s,               (char*)Bs[BUF][HN] + t16);                \
        gload_lds16(_s + (size_t)128 * K, (char*)Bs[BUF][HN] + t16 + 8192);     \
    }
// fragment reads (swizzled): A region row = wm*64+rb*16+l16, B = wn*32+cb*16+l16
#define LDA(BUF, HM, AF)                                                        \
    _Pragma("unroll") for (int rb = 0; rb < 4; rb++)                            \
    _Pragma("unroll") for (int kk = 0; kk < 2; kk++)                            \
        AF[rb][kk] = *(const bf16x8*)((const char*)As[BUF][HM] +                \
            (wm * 64 + rb * 16 + l16) * 128 + (((kk * 4 + quad) ^ (l16 & 7)) << 4));
#define LDB(BUF, HN, BF)                                                        \
    _Pragma("unroll") for (int cb = 0; cb < 2; cb++)                            \
    _Pragma("unroll") for (int kk = 0; kk < 2; kk++)                            \
        BF[cb][kk] = *(const bf16x8*)((const char*)Bs[BUF][HN] +                \
            (wn * 32 + cb * 16 + l16) * 128 + (((kk * 4 + quad) ^ (l16 & 7)) << 4));
#define MM(HM, HN, AF, BF)                                                      \
    {                                                                           \
        __builtin_amdgcn_s_setprio(1);                                          \
        _Pragma("unroll") for (int rb = 0; rb < 4; rb++)                        \
        _Pragma("unroll") for (int cb = 0; cb < 2; cb++) {                      \
            acc[HM][HN][rb][cb] = __builtin_amdgcn_mfma_f32_16x16x32_bf16(      \
                AF[rb][0], BF[cb][0], acc[HM][HN][rb][cb], 0, 0, 0);            \
            acc[HM][HN][rb][cb] = __builtin_amdgcn_mfma_f32_16x16x32_bf16(      \
                AF[rb][1], BF[cb][1], acc[HM][HN][rb][cb], 0, 0, 0);            \
        }                                                                       \
        __builtin_amdgcn_s_setprio(0);                                          \
    }
#define VM0 asm volatile("s_waitcnt vmcnt(0)" ::: "memory")
#define VM4 asm volatile("s_waitcnt vmcnt(4)" ::: "memory")
#define VM6 asm volatile("s_waitcnt vmcnt(6)" ::: "memory")
#define BARR __builtin_amdgcn_s_barrier()

    f32x4 acc[2][2][4][2];
#pragma unroll
    for (int a_ = 0; a_ < 2; a_++)
#pragma unroll
        for (int b_ = 0; b_ < 2; b_++)
#pragma unroll
            for (int c_ = 0; c_ < 4; c_++)
#pragma unroll
                for (int d_ = 0; d_ < 2; d_++)
                    acc[a_][b_][c_][d_] = (f32x4){0.f, 0.f, 0.f, 0.f};

    // ---- prologue: T0 complete + T1 {A0, B0, A1}; 3 newest half-tiles in flight
    STAGE_A(0, 0, 0); STAGE_A(0, 1, 0); STAGE_B(0, 0, 0); STAGE_B(0, 1, 0);
    STAGE_A(1, 0, 1); STAGE_B(1, 0, 1); STAGE_A(1, 1, 1);
    VM6;   // T0's 8 loads landed; T1.{A0,B0,A1} (6) may remain in flight
    BARR;

    for (int i = 0; i < NI; ++i) {
        const int TB = 2 * i + 1, T2 = 2 * i + 2, T3 = 2 * i + 3;
        const bool s2 = T2 < NT, s3 = T3 < NT;
        bf16x8 a[4][2], b0[2][2], b1[2][2];

        // p0: tile 2i, buf0, quadrant (0,0); stage TB.B1 (Bs[1][1] free since prev p7)
        LDA(0, 0, a); LDB(0, 0, b0);
        STAGE_B(1, 1, TB);
        MM(0, 0, a, b0);
        BARR;
        // p1: (0,1) — reuse a; stage T2.A0 (As[0][0] last read p0)
        LDB(0, 1, b1);
        if (s2) STAGE_A(0, 0, T2);
        MM(0, 1, a, b1);
        BARR;
        // p2: (1,0)
        LDA(0, 1, a); LDB(0, 0, b0);
        MM(1, 0, a, b0);
        BARR;
        // p3: (1,1); stage T2.B0 (Bs[0][0] last read p2); checkpoint: TB resident
        LDB(0, 1, b1);
        if (s2) STAGE_B(0, 0, T2);
        MM(1, 1, a, b1);
        if (i < NI - 1) { VM4; } else { VM0; }
        BARR;
        // p4: tile 2i+1, buf1, (0,0); stage T2.A1 (As[0][1] last read p2)
        LDA(1, 0, a); LDB(1, 0, b0);
        if (s2) STAGE_A(0, 1, T2);
        MM(0, 0, a, b0);
        BARR;
        // p5: (0,1); stage T2.B1 (Bs[0][1] last read p3) + T3.A0 (As[1][0] last read p4)
        LDB(1, 1, b1);
        if (s2) STAGE_B(0, 1, T2);
        if (s3) STAGE_A(1, 0, T3);
        MM(0, 1, a, b1);
        BARR;
        // p6: (1,0)
        LDA(1, 1, a); LDB(1, 0, b0);
        MM(1, 0, a, b0);
        BARR;
        // p7: (1,1); stage T3.B0 (Bs[1][0] last read p6) + T3.A1 (As[1][1] last read p6);
        //     checkpoint: T2 resident (3 newest half-tiles = T3 pieces allowed in flight)
        LDB(1, 1, b1);
        if (s3) { STAGE_B(1, 0, T3); STAGE_A(1, 1, T3); }
        MM(1, 1, a, b1);
        if (i < NI - 1) { VM6; BARR; }
    }
#undef STAGE_A
#undef STAGE_B
#undef LDA
#undef LDB
#undef MM
#undef VM0
#undef VM4
#undef VM6
#undef BARR

    // ---- epilogue ----
    if (by < 8) {
        // RoPE on Q/K (+0.125 scale on Q)
        const float sc = (by < 4) ? 0.125f : 1.0f;
        float fr[2][2];
#pragma unroll
        for (int hn = 0; hn < 2; hn++)
#pragma unroll
            for (int cb = 0; cb < 2; cb++)
                fr[hn][cb] = __expf(-(float)((hn * 32 + cb * 16 + l16) & ~1) *
                                    (9.210340371976184f / 64.0f));
        const float par = (l16 & 1) ? 1.f : -1.f;
#pragma unroll
        for (int hm = 0; hm < 2; hm++)
#pragma unroll
            for (int rb = 0; rb < 4; rb++)
#pragma unroll
                for (int r = 0; r < 4; r++) {
                    int row = m0 + wm * 128 + hm * 64 + rb * 16 + quad * 4 + r;
                    float p = (float)pos[row & (SEQ_LEN - 1)];
#pragma unroll
                    for (int hn = 0; hn < 2; hn++)
#pragma unroll
                        for (int cb = 0; cb < 2; cb++) {
                            float sn, cs;
                            __sincosf(p * fr[hn][cb], &sn, &cs);
                            float v  = acc[hm][hn][rb][cb][r];
                            float pt = __shfl_xor(v, 1);
                            C[(size_t)row * LDQK + n0 + wn * 64 + hn * 32 + cb * 16 + l16] =
                                __float2bfloat16((v * cs + par * pt * sn) * sc);
                        }
                }
    } else {
        // V transposed into Vtg[b][h][d][s'], key bits 2<->3 swapped
#pragma unroll
        for (int hm = 0; hm < 2; hm++)
#pragma unroll
            for (int rb = 0; rb < 4; rb++) {
                int row0e = m0 + wm * 128 + hm * 64 + rb * 16 + quad * 4;
                int bb = row0e >> 11, ss = row0e & (SEQ_LEN - 1);
                int ssw = (ss & ~12) | ((ss & 4) << 1) | ((ss & 8) >> 1);
#pragma unroll
                for (int hn = 0; hn < 2; hn++)
#pragma unroll
                    for (int cb = 0; cb < 2; cb++) {
                        int vcol = n0 + wn * 64 + hn * 32 + cb * 16 + l16 - 2048;
                        int hh = vcol >> 6, dd = vcol & 63;
                        ushort4 u;
                        u.x = (unsigned short)f2b(acc[hm][hn][rb][cb][0]);
                        u.y = (unsigned short)f2b(acc[hm][hn][rb][cb][1]);
                        u.z = (unsigned short)f2b(acc[hm][hn][rb][cb][2]);
                        u.w = (unsigned short)f2b(acc[hm][hn][rb][cb][3]);
                        *(ushort4*)(Vtg + ((size_t)(bb * NH + hh) * HD + dd) * SEQ_LEN + ssw) = u;
                    }
            }
    }
}

// ---------------------------------------------------------------------------
// GEMM (out-projection): C[M,N] = A[M,K] @ B[N,K]^T, 128x128 tile, BK=32,
// 4 waves, double-buffered LDS, chunk-XOR swizzle, XCD-chunked flat grid.
// (Unchanged from round 6 — passing.)
// ---------------------------------------------------------------------------
template <typename CT, bool FUSED>
__global__ __launch_bounds__(256) void gemm128(
    const __hip_bfloat16* __restrict__ A,
    const __hip_bfloat16* __restrict__ B,
    CT* __restrict__ C, int K, int ldc,
    __hip_bfloat16* __restrict__ Vtg, const int* __restrict__ pos, int nbx) {
    __shared__ __hip_bfloat16 As[2][128 * 32];
    __shared__ __hip_bfloat16 Bs[2][128 * 32];
    const int t    = threadIdx.x;
    const int wave = t >> 6;
    const int lane = t & 63;
    const int quad = lane >> 4;
    const int l16  = lane & 15;
    const int wy = wave >> 1, wx = wave & 1;

    const int nwg = gridDim.x;
    const int wg  = (blockIdx.x & 7) * (nwg >> 3) + (blockIdx.x >> 3);
    const int bx  = wg % nbx;
    const int by  = wg / nbx;
    const int m0 = bx * 128, n0 = by * 128;

    const int sr  = t >> 2;
    const int scx = (t & 3) ^ (sr & 3);

    const __hip_bfloat16* Ag = A + (size_t)(m0 + sr) * K + scx * 8;
    const __hip_bfloat16* Bg = B + (size_t)(n0 + sr) * K + scx * 8;

#define GSTAGE(BUF, K0)                                                         \
    {                                                                           \
        gload_lds16(Ag + (K0), (char*)As[BUF] + t * 16);                        \
        gload_lds16(Ag + (size_t)64 * K + (K0), (char*)As[BUF] + (t + 256) * 16); \
        gload_lds16(Bg + (K0), (char*)Bs[BUF] + t * 16);                        \
        gload_lds16(Bg + (size_t)64 * K + (K0), (char*)Bs[BUF] + (t + 256) * 16); \
    }

    f32x4 acc[4][4];
#pragma unroll
    for (int i = 0; i < 4; i++)
#pragma unroll
        for (int j = 0; j < 4; j++) acc[i][j] = (f32x4){0.f, 0.f, 0.f, 0.f};

    const int NT = K >> 5;
    GSTAGE(0, 0);
    __syncthreads();
    int cur = 0;
    for (int t32 = 0; t32 < NT; ++t32) {
        if (t32 + 1 < NT) GSTAGE(cur ^ 1, (t32 + 1) * 32);

        bf16x8 af[4], bfr[4];
#pragma unroll
        for (int rb = 0; rb < 4; rb++) {
            int row = wy * 64 + rb * 16 + l16;
            af[rb] = *(const bf16x8*)((const char*)As[cur] + row * 64 +
                                      ((quad ^ (row & 3)) << 4));
        }
#pragma unroll
        for (int cb = 0; cb < 4; cb++) {
            int row = wx * 64 + cb * 16 + l16;
            bfr[cb] = *(const bf16x8*)((const char*)Bs[cur] + row * 64 +
                                       ((quad ^ (row & 3)) << 4));
        }
#pragma unroll
        for (int rb = 0; rb < 4; rb++)
#pragma unroll
            for (int cb = 0; cb < 4; cb++)
                acc[rb][cb] = __builtin_amdgcn_mfma_f32_16x16x32_bf16(
                    af[rb], bfr[cb], acc[rb][cb], 0, 0, 0);

        __syncthreads();
        cur ^= 1;
    }
#undef GSTAGE

    if (!FUSED || by < 16) {
        if constexpr (FUSED) {
            const float sc = (by < 8) ? 0.125f : 1.0f;
            float fr[4];
#pragma unroll
            for (int cb = 0; cb < 4; cb++) {
                int i = ((cb * 16 + l16) & 63) >> 1;
                fr[cb] = __expf(-(float)(2 * i) * (9.210340371976184f / 64.0f));
            }
            const float par = (l16 & 1) ? 1.f : -1.f;
#pragma unroll
            for (int rb = 0; rb < 4; rb++)
#pragma unroll
                for (int r = 0; r < 4; r++) {
                    int row = m0 + wy * 64 + rb * 16 + quad * 4 + r;
                    float p = (float)pos[row & (SEQ_LEN - 1)];
#pragma unroll
                    for (int cb = 0; cb < 4; cb++) {
                        float sn, cs;
                        __sincosf(p * fr[cb], &sn, &cs);
                        float v  = acc[rb][cb][r];
                        float pt = __shfl_xor(v, 1);
                        acc[rb][cb][r] = (v * cs + par * pt * sn) * sc;
                    }
                }
        }
#pragma unroll
        for (int rb = 0; rb < 4; rb++)
#pragma unroll
            for (int r = 0; r < 4; r++) {
                size_t ro = (size_t)(m0 + wy * 64 + rb * 16 + quad * 4 + r) * ldc;
#pragma unroll
                for (int cb = 0; cb < 4; cb++)
                    store_c(&C[ro + n0 + wx * 64 + cb * 16 + l16], acc[rb][cb][r]);
            }
    } else {
#pragma unroll
        for (int rb = 0; rb < 4; rb++) {
            int row0 = m0 + wy * 64 + rb * 16 + quad * 4;
            int bb = row0 >> 11, ss = row0 & (SEQ_LEN - 1);
            int ssw = (ss & ~12) | ((ss & 4) << 1) | ((ss & 8) >> 1);
#pragma unroll
            for (int cb = 0; cb < 4; cb++) {
                int vcol = n0 + wx * 64 + cb * 16 + l16 - 2048;
                int hh = vcol >> 6, dd = vcol & 63;
                ushort4 u;
                u.x = (unsigned short)f2b(acc[rb][cb][0]);
                u.y = (unsigned short)f2b(acc[rb][cb][1]);
                u.z = (unsigned short)f2b(acc[rb][cb][2]);
                u.w = (unsigned short)f2b(acc[rb][cb][3]);
                *(ushort4*)(Vtg + ((size_t)(bb * NH + hh) * HD + dd) * SEQ_LEN + ssw) = u;
            }
        }
    }
}

// ---------------------------------------------------------------------------
// Causal MFMA flash attention — 32x32x16, in-register P (unchanged, passing).
// ---------------------------------------------------------------------------
__global__ __launch_bounds__(256, 2) void attn_kernel(
    const __hip_bfloat16* __restrict__ QK,
    const __hip_bfloat16* __restrict__ Vtg,
    __hip_bfloat16* __restrict__ O) {
    __shared__ __hip_bfloat16 Ks[2][64 * 64];  // [buf][key][d]  XOR-swizzled
    __shared__ __hip_bfloat16 Vs[2][64 * 64];  // [buf][d][key'] XOR-swizzled

    const int t    = threadIdx.x;
    const int wave = t >> 6;
    const int lane = t & 63;
    const int l5   = lane & 31;
    const int hi   = lane >> 5;
    const int id   = blockIdx.x;
    const int qtc  = id >> 5;
    const int hb   = id & 31;
    const int h    = hb & 15;
    const int b    = hb >> 4;
    const int qt   = (qtc < 8) ? (15 - qtc) : (qtc - 8);

    const int row0 = qt * 128 + wave * 32;
    const int ktd  = (row0 + 31) >> 6;
    const int KTM  = 2 * qt + 1;

    const int sr  = t >> 3;
    const int scx = (t & 7) ^ (sr & 7);

    const __hip_bfloat16* kbase = QK + (size_t)(b * SEQ_LEN) * LDQK + DM + h * HD;
    const __hip_bfloat16* vbase = Vtg + (size_t)((b * NH + h) * HD) * SEQ_LEN;

    bf16x8 qf[4];
    {
        const __hip_bfloat16* qp =
            QK + (size_t)(b * SEQ_LEN + row0 + l5) * LDQK + h * HD + hi * 8;
#pragma unroll
        for (int dc = 0; dc < 4; dc++) qf[dc] = *(const bf16x8*)(qp + dc * 16);
    }

    f32x16 o0, o1;
#pragma unroll
    for (int i = 0; i < 16; i++) { o0[i] = 0.f; o1[i] = 0.f; }
    float l_acc = 0.f;

#define STAGE(BUF, KT)                                                          \
    {                                                                           \
        gload_lds16(kbase + (size_t)((KT) * 64 + sr) * LDQK + scx * 8,          \
                    (char*)&Ks[BUF][0] + t * 16);                               \
        gload_lds16(kbase + (size_t)((KT) * 64 + sr + 32) * LDQK + scx * 8,     \
                    (char*)&Ks[BUF][0] + (t + 256) * 16);                       \
        gload_lds16(vbase + (size_t)sr * SEQ_LEN + (KT) * 64 + scx * 8,         \
                    (char*)&Vs[BUF][0] + t * 16);                               \
        gload_lds16(vbase + (size_t)(sr + 32) * SEQ_LEN + (KT) * 64 + scx * 8,  \
                    (char*)&Vs[BUF][0] + (t + 256) * 16);                       \
    }

#define LFRAG(BASE, ROW, CH)                                                    \
    (*(const bf16x8*)((const char*)(BASE) + (ROW) * 128 + ((((CH) ^ ((ROW) & 7))) << 4)))

#define MKPA(S, PA0, PA1)                                                       \
    {                                                                           \
        float p_[16];                                                           \
        _Pragma("unroll") for (int r = 0; r < 16; r++) {                        \
            p_[r] = __expf((S)[r]);                                             \
            l_acc += p_[r];                                                     \
        }                                                                       \
        _Pragma("unroll") for (int j = 0; j < 8; j++) {                         \
            PA0[j] = f2b(p_[j]);                                                \
            PA1[j] = f2b(p_[8 + j]);                                            \
        }                                                                       \
    }

#define TRIP(BUF, KT)                                                           \
    {                                                                           \
        f32x16 s0, s1;                                                          \
        _Pragma("unroll") for (int i = 0; i < 16; i++) { s0[i] = 0.f; s1[i] = 0.f; } \
        __builtin_amdgcn_s_setprio(1);                                          \
        _Pragma("unroll") for (int dc = 0; dc < 4; dc++) {                      \
            bf16x8 k0f = LFRAG(Ks[BUF], l5, dc * 2 + hi);                       \
            bf16x8 k1f = LFRAG(Ks[BUF], 32 + l5, dc * 2 + hi);                  \
            s0 = __builtin_amdgcn_mfma_f32_32x32x16_bf16(k0f, qf[dc], s0, 0, 0, 0); \
            s1 = __builtin_amdgcn_mfma_f32_32x32x16_bf16(k1f, qf[dc], s1, 0, 0, 0); \
        }                                                                       \
        __builtin_amdgcn_s_setprio(0);                                          \
        if ((KT) == ktd) {                                                      \
            int qrow = row0 + l5;                                               \
            _Pragma("unroll") for (int r = 0; r < 16; r++) {                    \
                int key = (KT) * 64 + (r & 3) + 8 * (r >> 2) + 4 * hi;          \
                if (key > qrow) s0[r] = -1e30f;                                 \
                if (key + 32 > qrow) s1[r] = -1e30f;                            \
            }                                                                   \
        }                                                                       \
        bf16x8 pa0, pa1, pa2, pa3;                                              \
        MKPA(s0, pa0, pa1);                                                     \
        MKPA(s1, pa2, pa3);                                                     \
        __builtin_amdgcn_s_setprio(1);                                          \
        _Pragma("unroll") for (int kc = 0; kc < 4; kc++) {                      \
            bf16x8 v0f = LFRAG(Vs[BUF], l5, kc * 2 + hi);                       \
            bf16x8 v1f = LFRAG(Vs[BUF], 32 + l5, kc * 2 + hi);                  \
            bf16x8 paf = (kc == 0) ? pa0 : (kc == 1) ? pa1 : (kc == 2) ? pa2 : pa3; \
            o0 = __builtin_amdgcn_mfma_f32_32x32x16_bf16(paf, v0f, o0, 0, 0, 0); \
            o1 = __builtin_amdgcn_mfma_f32_32x32x16_bf16(paf, v1f, o1, 0, 0, 0); \
        }                                                                       \
        __builtin_amdgcn_s_setprio(0);                                          \
    }

    STAGE(0, 0);
    for (int kt = 0; kt <= KTM; ++kt) {
        const int buf = kt & 1;
        __syncthreads();
        if (kt < KTM) STAGE(buf ^ 1, kt + 1);
        if (kt <= ktd) TRIP(buf, kt);
    }

    l_acc += __shfl_xor(l_acc, 32);
    float inv = 1.0f / l_acc;
#pragma unroll
    for (int r = 0; r < 16; r++) {
        int crow  = (r & 3) + 8 * (r >> 2) + 4 * hi;
        float invr = __shfl(inv, crow);
        size_t ro = (size_t)(b * SEQ_LEN + row0 + crow) * DM + h * HD;
        O[ro + l5]      = __float2bfloat16(o0[r] * invr);
        O[ro + 32 + l5] = __float2bfloat16(o1[r] * invr);
    }
#undef STAGE
#undef LFRAG
#undef MKPA
#undef TRIP
}

// ---------------------------------------------------------------------------
// Workspace (40 MiB of 48):
//   [0,8)    xb [4096x1024] bf16, reused as Ab (attn output)
//   [8,14)   Wqkvb [3072x1024] bf16
//   [14,16)  Wob [1024x1024] bf16
//   [16,32)  QKb [4096x2048] bf16 (Q roped+scaled, K roped — fused in GEMM)
//   [32,40)  Vtg [2][16][64][2048] bf16 (key bits 2<->3 swapped layout)
// ---------------------------------------------------------------------------
extern "C" void kernel_launch(void* const* d_in, const int* in_sizes, int n_in,
                              void* d_out, int out_size, void* d_ws, size_t ws_size,
                              hipStream_t stream) {
    const float* x  = (const float*)d_in[0];
    const float* Wq = (const float*)d_in[1];
    const float* Wk = (const float*)d_in[2];
    const float* Wv = (const float*)d_in[3];
    const float* Wo = (const float*)d_in[4];
    const int* pos = (const int*)d_in[6];
    float* out = (float*)d_out;

    char* w = (char*)d_ws;
    const size_t MiB = 1024 * 1024;
    __hip_bfloat16* xb    = (__hip_bfloat16*)(w + 0 * MiB);
    __hip_bfloat16* Ab    = (__hip_bfloat16*)(w + 0 * MiB);  // reuse after QKV gemm
    __hip_bfloat16* Wqkvb = (__hip_bfloat16*)(w + 8 * MiB);
    __hip_bfloat16* Wob   = (__hip_bfloat16*)(w + 14 * MiB);
    __hip_bfloat16* QKb   = (__hip_bfloat16*)(w + 16 * MiB);
    __hip_bfloat16* Vtg   = (__hip_bfloat16*)(w + 32 * MiB);

    cvt_all<<<8192, 256, 0, stream>>>(x, Wq, Wk, Wv, Wo, xb, Wqkvb, Wob);

    // QKV projection: 256^2 8-phase counted-vmcnt GEMM, 192 blocks (24/XCD)
    gemm256_qkv<<<192, 512, 0, stream>>>(xb, Wqkvb, QKb, Vtg, pos);

    attn_kernel<<<512, 256, 0, stream>>>(QKb, Vtg, Ab);

    gemm128<float, false><<<(NR / 128) * (DM / 128), 256, 0, stream>>>(
        Ab, Wob, out, DM, DM, nullptr, nullptr, NR / 128);
}